// Round 6
// baseline (61.903 us; speedup 1.0000x reference)
//
#include <hip/hip_runtime.h>
#include <utility>

#define DEV __device__ __forceinline__

constexpr int NV = 16;
constexpr float STEP = 0.1f;
constexpr int MAX_ITER = 20;
constexpr int LDA = 20;  // padded LDS row stride: 80 B -> 2-way bank alias only (free)

// ---- compile-time for loop (DPP ctrl / register indices must be ICEs) ----
template <class F, int... Is>
DEV void sf_impl(F&& f, std::integer_sequence<int, Is...>) {
  (f(std::integral_constant<int, Is>{}), ...);
}
template <int N, class F>
DEV void static_for(F&& f) {
  sf_impl(f, std::make_integer_sequence<int, N>{});
}

// ---- broadcast lane Q within each quad via DPP quad_perm (pure VALU, no LDS) ----
template <int Q>
DEV float qbcast(float v) {
  int iv = __float_as_int(v);
  int r = __builtin_amdgcn_update_dpp(iv, iv, Q * 0x55, 0xF, 0xF, true);
  return __int_as_float(r);
}

DEV float rcp_fast(float x) { return __builtin_amdgcn_rcpf(x); }

// One quad per TWO systems; lane l owns rows {4l..4l+3} of both. The two
// independent Gauss-Jordan chains interleave inside one instruction stream,
// so every serial link (rcp -> DPP bcast -> f-mul) of system 0 is filled by
// system 1's work -- ILP replaces the missing TLP (grid is thread-limited
// to 1 wave/SIMD at this decomposition).
// u-substitution: solve (A + diag(3y^2/cos)) u = b, delta = u/cos.
__global__ __attribute__((amdgpu_flat_work_group_size(256, 256),
                          amdgpu_waves_per_eu(1, 1)))
void newton16(const float* __restrict__ y0, const float* __restrict__ xin,
              const float* __restrict__ Ain, float* __restrict__ out, int B) {
  __shared__ float Alds[NV * LDA];
  {
    const int t = threadIdx.x;
    if (t < 64) {
      const int row = t >> 2, seg = t & 3;
      float4 a = *reinterpret_cast<const float4*>(Ain + row * NV + seg * 4);
      *reinterpret_cast<float4*>(&Alds[row * LDA + seg * 4]) = a;
    }
  }
  __syncthreads();  // full blocks: every thread reaches this; guard below

  const int tid = blockIdx.x * blockDim.x + threadIdx.x;
  const int qi = tid >> 2, l = tid & 3;
  const int s0 = qi * 2;  // this quad's pair of systems
  if (s0 >= B) return;

  float y[2][4], x[2][4];
  static_for<2>([&](auto SS) {
    constexpr int s = SS.value;
    float4 t = *reinterpret_cast<const float4*>(y0 + (s0 + s) * NV + 4 * l);
    y[s][0] = t.x; y[s][1] = t.y; y[s][2] = t.z; y[s][3] = t.w;
    float4 u = *reinterpret_cast<const float4*>(xin + (s0 + s) * NV + 4 * l);
    x[s][0] = u.x; x[s][1] = u.y; x[s][2] = u.z; x[s][3] = u.w;
  });

  float eqf[4], neqf[4];
#pragma unroll
  for (int q = 0; q < 4; ++q) {
    eqf[q] = (l == q) ? 1.0f : 0.0f;
    neqf[q] = 1.0f - eqf[q];
  }

  const float* __restrict__ Arow0 = &Alds[(4 * l) * LDA];

#pragma unroll 1  // ~2k-instr body; full unroll would thrash I-cache
  for (int it = 0; it < MAX_ITER; ++it) {
    // 1) trig + diagonal terms + b init, both systems (independent chains)
    float s4[2][4], rc[2][4], tdiag[2][4], b[2][4];
    static_for<2>([&](auto SS) {
      constexpr int s = SS.value;
#pragma unroll
      for (int m = 0; m < 4; ++m) {
        float yy = y[s][m];
        float y2 = yy * yy;
        s4[s][m] = __sinf(yy);
        float c = __cosf(yy);
        rc[s][m] = rcp_fast(c);
        tdiag[s][m] = 3.0f * y2 * rc[s][m];
        b[s][m] = x[s][m] - y2 * yy;
      }
    });

    // 2) sin vectors via quad broadcast (32 DPP)
    float sf[2][16];
    static_for<16>([&](auto JJ) {
      constexpr int j = JJ.value;
      sf[0][j] = qbcast<(j >> 2)>(s4[0][j & 3]);
      sf[1][j] = qbcast<(j >> 2)>(s4[1][j & 3]);
    });

    // 3) M <- A (LDS, read per system: dest regs are M's directly, no copies)
    //    fused with residual b -= A*sin(y)
    float M[2][4][16];
    static_for<2>([&](auto SS) {
      constexpr int s = SS.value;
      static_for<4>([&](auto MM) {
        constexpr int m = MM.value;
        static_for<4>([&](auto TT) {
          constexpr int t = TT.value;
          float4 a4 = *reinterpret_cast<const float4*>(Arow0 + m * LDA + 4 * t);
          M[s][m][4 * t + 0] = a4.x; M[s][m][4 * t + 1] = a4.y;
          M[s][m][4 * t + 2] = a4.z; M[s][m][4 * t + 3] = a4.w;
          b[s][m] = __builtin_fmaf(-a4.x, sf[s][4 * t + 0], b[s][m]);
          b[s][m] = __builtin_fmaf(-a4.y, sf[s][4 * t + 1], b[s][m]);
          b[s][m] = __builtin_fmaf(-a4.z, sf[s][4 * t + 2], b[s][m]);
          b[s][m] = __builtin_fmaf(-a4.w, sf[s][4 * t + 3], b[s][m]);
        });
      });
    });
    // diag add: row 4l+m's diagonal is col block t==l, slot m
    static_for<2>([&](auto SS) {
      constexpr int s = SS.value;
      static_for<4>([&](auto MM) {
        constexpr int m = MM.value;
        static_for<4>([&](auto TT) {
          constexpr int t = TT.value;
          M[s][m][4 * t + m] = __builtin_fmaf(eqf[t], tdiag[s][m], M[s][m][4 * t + m]);
        });
      });
    });

    // 4) unpivoted Gauss-Jordan, two interleaved chains
    float dginv[2][4] = {{0.f, 0.f, 0.f, 0.f}, {0.f, 0.f, 0.f, 0.f}};
    static_for<16>([&](auto KK) {
      constexpr int k = KK.value;
      constexpr int q = k >> 2, mk = k & 3;
      float inv[2], bk[2], f[2][4];
      static_for<2>([&](auto SS) {
        constexpr int s = SS.value;
        float invl = rcp_fast(M[s][mk][k]);  // local rcp before bcast
        inv[s] = qbcast<q>(invl);
        bk[s] = qbcast<q>(b[s][mk]);
      });
      static_for<2>([&](auto SS) {
        constexpr int s = SS.value;
#pragma unroll
        for (int m = 0; m < 4; ++m) f[s][m] = M[s][m][k] * inv[s];
        f[s][mk] *= neqf[q];                        // owner keeps its pivot row
        dginv[s][mk] = (l == q) ? inv[s] : dginv[s][mk];
#pragma unroll
        for (int m = 0; m < 4; ++m) b[s][m] = __builtin_fmaf(-f[s][m], bk[s], b[s][m]);
      });
      static_for<16 - k - 1>([&](auto JJ) {
        constexpr int j = k + 1 + JJ.value;
        static_for<2>([&](auto SS) {
          constexpr int s = SS.value;
          float rkj = qbcast<q>(M[s][mk][j]);
#pragma unroll
          for (int m = 0; m < 4; ++m) M[s][m][j] = __builtin_fmaf(-f[s][m], rkj, M[s][m][j]);
        });
      });
    });

    // 5) u = b*dginv ; delta = u/cos ; y += STEP*delta
    static_for<2>([&](auto SS) {
      constexpr int s = SS.value;
#pragma unroll
      for (int m = 0; m < 4; ++m) {
        float u = b[s][m] * dginv[s][m];
        y[s][m] = __builtin_fmaf(STEP, u * rc[s][m], y[s][m]);
      }
    });
  }

  static_for<2>([&](auto SS) {
    constexpr int s = SS.value;
    float4 o;
    o.x = y[s][0]; o.y = y[s][1]; o.z = y[s][2]; o.w = y[s][3];
    *reinterpret_cast<float4*>(out + (s0 + s) * NV + 4 * l) = o;
  });
}

extern "C" void kernel_launch(void* const* d_in, const int* in_sizes, int n_in,
                              void* d_out, int out_size, void* d_ws, size_t ws_size,
                              hipStream_t stream) {
  const float* y = (const float*)d_in[0];
  const float* x = (const float*)d_in[1];
  const float* A = (const float*)d_in[2];
  float* out = (float*)d_out;
  const int B = in_sizes[0] / NV;  // 32768
  const int threads = (B / 2) * 4; // one quad per PAIR of systems
  dim3 block(256);
  dim3 grid((threads + block.x - 1) / block.x);
  hipLaunchKernelGGL(newton16, grid, block, 0, stream, y, x, A, out, B);
}

// Round 8
// 52.401 us; speedup vs baseline: 1.1813x; 1.1813x over previous
//
#include <hip/hip_runtime.h>
#include <utility>

#define DEV __device__ __forceinline__

constexpr int NV = 16;
constexpr float STEP = 0.1f;
constexpr int T_BUILD = 16;  // exact Newton iters (fresh factorization each)
constexpr int T_APPLY = 4;   // frozen-factorization iters (reuse last build's factors)
constexpr int LDA = 20;      // padded LDS row stride: 80 B -> 2-way bank alias only (free)

// ---- compile-time for loop (DPP ctrl / register indices must be ICEs) ----
template <class F, int... Is>
DEV void sf_impl(F&& f, std::integer_sequence<int, Is...>) {
  (f(std::integral_constant<int, Is>{}), ...);
}
template <int N, class F>
DEV void static_for(F&& f) {
  sf_impl(f, std::make_integer_sequence<int, N>{});
}

// ---- broadcast lane Q within each quad via DPP quad_perm (intrinsic: the
// compiler's hazard recognizer manages DPP wait states -- R7's inline-asm
// DPP tripped exactly that hazard) ----
template <int Q>
DEV float qbcast(float v) {
  int iv = __float_as_int(v);
  int r = __builtin_amdgcn_update_dpp(iv, iv, Q * 0x55, 0xF, 0xF, true);
  return __int_as_float(r);
}

DEV float rcp_fast(float x) { return __builtin_amdgcn_rcpf(x); }

// One full Newton iteration: fresh M = A + diag(3y^2/cos), residual, and
// Gauss-Jordan solve. If STORE, the per-step elimination factors f[] and the
// pivot inverses survive (nfS/dginv) for the frozen-apply iterations.
// Liveness note: M's column k dies at GJ step k exactly when nfS[k] is born,
// so STORE adds ~no peak register pressure.
template <bool STORE>
DEV void newton_full_iter(float (&y)[4], const float (&x)[4],
                          const float* __restrict__ Arow0,
                          const float (&eqf)[4], const float (&neqf)[4],
                          int l, float (&nfS)[16][4], float (&dginv)[4]) {
  // 1) M <- A (LDS reads issue first; waitcnt lands before first use)
  float M[4][16];
  static_for<4>([&](auto MM) {
    constexpr int m = MM.value;
    static_for<4>([&](auto TT) {
      constexpr int t = TT.value;
      float4 a4 = *reinterpret_cast<const float4*>(Arow0 + m * LDA + 4 * t);
      M[m][4 * t + 0] = a4.x; M[m][4 * t + 1] = a4.y;
      M[m][4 * t + 2] = a4.z; M[m][4 * t + 3] = a4.w;
    });
  });

  // 2) trig + diag term + b init (hw v_sin/v_cos fine at O(1) rad)
  float s4[4], rc[4], tdiag[4], b[4];
#pragma unroll
  for (int m = 0; m < 4; ++m) {
    float yy = y[m];
    float y2 = yy * yy;
    s4[m] = __sinf(yy);
    float c = __cosf(yy);
    rc[m] = rcp_fast(c);
    tdiag[m] = 3.0f * y2 * rc[m];
    b[m] = x[m] - y2 * yy;
  }
  float sf[16];
  static_for<16>([&](auto JJ) {
    constexpr int j = JJ.value;
    sf[j] = qbcast<(j >> 2)>(s4[j & 3]);
  });

  // 3) residual b -= A*sin(y)  (uses M == A, before diag add)
  static_for<4>([&](auto MM) {
    constexpr int m = MM.value;
    static_for<16>([&](auto JJ) {
      constexpr int j = JJ.value;
      b[m] = __builtin_fmaf(-M[m][j], sf[j], b[m]);
    });
  });
  // diag add: row 4l+m's diagonal is col block t==l, slot m
  static_for<4>([&](auto MM) {
    constexpr int m = MM.value;
    static_for<4>([&](auto TT) {
      constexpr int t = TT.value;
      M[m][4 * t + m] = __builtin_fmaf(eqf[t], tdiag[m], M[m][4 * t + m]);
    });
  });

  // 4) unpivoted Gauss-Jordan (M diag-dominant by construction)
  static_for<16>([&](auto KK) {
    constexpr int k = KK.value;
    constexpr int q = k >> 2, mk = k & 3;
    float invl = rcp_fast(M[mk][k]);  // local rcp before bcast
    float inv = qbcast<q>(invl);
    float bk = qbcast<q>(b[mk]);
    float f[4];
#pragma unroll
    for (int m = 0; m < 4; ++m) f[m] = M[m][k] * inv;
    f[mk] *= neqf[q];                      // owner lane keeps its pivot row
    dginv[mk] = (l == q) ? inv : dginv[mk];  // capture own pivot inverse
    static_for<16 - k - 1>([&](auto JJ) {
      constexpr int j = k + 1 + JJ.value;
      float rkj = qbcast<q>(M[mk][j]);
#pragma unroll
      for (int m = 0; m < 4; ++m) M[m][j] = __builtin_fmaf(-f[m], rkj, M[m][j]);
    });
#pragma unroll
    for (int m = 0; m < 4; ++m) b[m] = __builtin_fmaf(-f[m], bk, b[m]);
    if constexpr (STORE) {
#pragma unroll
      for (int m = 0; m < 4; ++m) nfS[k][m] = f[m];
    }
  });

  // 5) u = b*dginv ; delta = u/cos ; y += STEP*delta
#pragma unroll
  for (int m = 0; m < 4; ++m) {
    float u = b[m] * dginv[m];
    y[m] = __builtin_fmaf(STEP, u * rc[m], y[m]);
  }
}

// Frozen-factorization iteration: fresh residual, replay stored elimination.
// ~215 VALU ops vs ~960 for a full iteration. Same fixed point as exact
// Newton (residual is exact), only the late-trajectory direction is approx.
DEV void newton_apply_iter(float (&y)[4], const float (&x)[4],
                           const float* __restrict__ Arow0,
                           const float (&nfS)[16][4], const float (&dginv)[4]) {
  float s4[4], rc[4], b[4];
#pragma unroll
  for (int m = 0; m < 4; ++m) {
    float yy = y[m];
    float y2 = yy * yy;
    s4[m] = __sinf(yy);
    rc[m] = rcp_fast(__cosf(yy));
    b[m] = x[m] - y2 * yy;
  }
  float sf[16];
  static_for<16>([&](auto JJ) {
    constexpr int j = JJ.value;
    sf[j] = qbcast<(j >> 2)>(s4[j & 3]);
  });
  // residual from A (LDS re-read; LDS pipe is idle anyway)
  static_for<4>([&](auto MM) {
    constexpr int m = MM.value;
    static_for<4>([&](auto TT) {
      constexpr int t = TT.value;
      float4 a4 = *reinterpret_cast<const float4*>(Arow0 + m * LDA + 4 * t);
      b[m] = __builtin_fmaf(-a4.x, sf[4 * t + 0], b[m]);
      b[m] = __builtin_fmaf(-a4.y, sf[4 * t + 1], b[m]);
      b[m] = __builtin_fmaf(-a4.z, sf[4 * t + 2], b[m]);
      b[m] = __builtin_fmaf(-a4.w, sf[4 * t + 3], b[m]);
    });
  });
  // replay stored elimination on b
  static_for<16>([&](auto KK) {
    constexpr int k = KK.value;
    constexpr int q = k >> 2, mk = k & 3;
    float bk = qbcast<q>(b[mk]);
#pragma unroll
    for (int m = 0; m < 4; ++m) b[m] = __builtin_fmaf(-nfS[k][m], bk, b[m]);
  });
#pragma unroll
  for (int m = 0; m < 4; ++m) {
    float u = b[m] * dginv[m];
    y[m] = __builtin_fmaf(STEP, u * rc[m], y[m]);
  }
}

// One quad per system; lane l owns rows {4l..4l+3}. u-substitution:
// solve (A + diag(3y^2/cos)) u = b, delta = u/cos. A staged in LDS.
__global__ __attribute__((amdgpu_flat_work_group_size(256, 256),
                          amdgpu_waves_per_eu(2, 2)))
void newton16(const float* __restrict__ y0, const float* __restrict__ xin,
              const float* __restrict__ Ain, float* __restrict__ out, int B) {
  __shared__ float Alds[NV * LDA];
  {
    const int t = threadIdx.x;
    if (t < 64) {
      const int row = t >> 2, seg = t & 3;
      float4 a = *reinterpret_cast<const float4*>(Ain + row * NV + seg * 4);
      *reinterpret_cast<float4*>(&Alds[row * LDA + seg * 4]) = a;
    }
  }
  __syncthreads();

  const int tid = blockIdx.x * blockDim.x + threadIdx.x;
  const int g = tid >> 2, l = tid & 3;
  if (g >= B) return;

  float y[4], x[4];
  {
    float4 t = *reinterpret_cast<const float4*>(y0 + g * NV + 4 * l);
    y[0] = t.x; y[1] = t.y; y[2] = t.z; y[3] = t.w;
    float4 u = *reinterpret_cast<const float4*>(xin + g * NV + 4 * l);
    x[0] = u.x; x[1] = u.y; x[2] = u.z; x[3] = u.w;
  }

  float eqf[4], neqf[4];
#pragma unroll
  for (int q = 0; q < 4; ++q) {
    eqf[q] = (l == q) ? 1.0f : 0.0f;
    neqf[q] = 1.0f - eqf[q];
  }

  const float* __restrict__ Arow0 = &Alds[(4 * l) * LDA];

  float nfS[16][4];  // frozen elimination factors (filled by the peeled iter)
  float dginv[4] = {1.0f, 1.0f, 1.0f, 1.0f};

#pragma unroll 1  // keep ~1k-instr body; full unroll would thrash I-cache
  for (int it = 0; it < T_BUILD - 1; ++it)
    newton_full_iter<false>(y, x, Arow0, eqf, neqf, l, nfS, dginv);
  // peeled last build iter: stores factors (zero-cost: nfS aliases f's regs)
  newton_full_iter<true>(y, x, Arow0, eqf, neqf, l, nfS, dginv);

#pragma unroll 1
  for (int it = 0; it < T_APPLY; ++it)
    newton_apply_iter(y, x, Arow0, nfS, dginv);

  float4 o;
  o.x = y[0]; o.y = y[1]; o.z = y[2]; o.w = y[3];
  *reinterpret_cast<float4*>(out + g * NV + 4 * l) = o;
}

extern "C" void kernel_launch(void* const* d_in, const int* in_sizes, int n_in,
                              void* d_out, int out_size, void* d_ws, size_t ws_size,
                              hipStream_t stream) {
  const float* y = (const float*)d_in[0];
  const float* x = (const float*)d_in[1];
  const float* A = (const float*)d_in[2];
  float* out = (float*)d_out;
  const int B = in_sizes[0] / NV;  // 32768
  const int threads = B * 4;       // one quad per system
  dim3 block(256);
  dim3 grid((threads + block.x - 1) / block.x);
  hipLaunchKernelGGL(newton16, grid, block, 0, stream, y, x, A, out, B);
}